// Round 1
// baseline (840.399 us; speedup 1.0000x reference)
//
#include <hip/hip_runtime.h>
#include <cfloat>

#define BB 64
#define NN 1024
#define MM 128
#define DD 256
#define MASKV (-1e30f)

// ---------------------------------------------------------------------------
// K1: sub0[b,n] = c[b,n,:].w0 ; qtermM[b,m] = q[b,m,:].w1 + bias[m] + MASK*(1-qm)
// one wave per row, float4 per lane, shuffle reduce
// ---------------------------------------------------------------------------
__global__ __launch_bounds__(256) void k_dots(
    const float* __restrict__ c, const float* __restrict__ q,
    const int* __restrict__ qmask,
    const float* __restrict__ w0, const float* __restrict__ w1,
    const float* __restrict__ bias,
    float* __restrict__ sub0, float* __restrict__ qtermM) {
  int wave = (blockIdx.x * blockDim.x + threadIdx.x) >> 6;
  int lane = threadIdx.x & 63;
  const int total = BB * NN + BB * MM;
  if (wave >= total) return;
  const float* row;
  const float* w;
  if (wave < BB * NN) { row = c + (size_t)wave * DD; w = w0; }
  else                { row = q + (size_t)(wave - BB * NN) * DD; w = w1; }
  float4 v  = *(const float4*)(row + lane * 4);
  float4 wv = *(const float4*)(w   + lane * 4);
  float s = v.x * wv.x + v.y * wv.y + v.z * wv.z + v.w * wv.w;
  #pragma unroll
  for (int off = 32; off > 0; off >>= 1) s += __shfl_xor(s, off, 64);
  if (lane == 0) {
    if (wave < BB * NN) {
      sub0[wave] = s;
    } else {
      int r = wave - BB * NN;
      int m = r & (MM - 1);
      qtermM[r] = s + bias[m] + (qmask[r] ? 0.0f : MASKV);
    }
  }
}

// ---------------------------------------------------------------------------
// K2: sub2 tile GEMM (64 rows x 128 m, K=256) + fused row softmax (over m).
// Writes S_ (row-softmaxed) and T = sub2 + sub0 + MASK*(1-cmask) for col pass.
// Per-thread tile: 8 rows x 4 m.  tx = t&31 -> m = tx + j*32 ; ty = t>>5 ->
// rows ty*8+i.  Row stats reduce across a 32-lane half-wave via shfl_xor.
// ---------------------------------------------------------------------------
__global__ __launch_bounds__(256) void k_score(
    const float* __restrict__ c, const float* __restrict__ q,
    const int* __restrict__ cmask, const float* __restrict__ wm,
    const float* __restrict__ sub0, const float* __restrict__ qtermM,
    float* __restrict__ S_, float* __restrict__ T) {
  __shared__ float cw[64 * 32];    // [r][dd], stride 32 (reads are broadcast)
  __shared__ float qs[128 * 36];   // [m][dd], stride 36 (16B aligned, low-conflict)
  const int b = blockIdx.y;
  const int n0 = blockIdx.x * 64;
  const int t = threadIdx.x;
  const int tx = t & 31, ty = t >> 5;

  float acc[8][4];
  #pragma unroll
  for (int i = 0; i < 8; i++)
    #pragma unroll
    for (int j = 0; j < 4; j++) acc[i][j] = 0.0f;

  float qt[4];
  #pragma unroll
  for (int j = 0; j < 4; j++) qt[j] = qtermM[b * MM + tx + j * 32];

  for (int k0 = 0; k0 < DD; k0 += 32) {
    __syncthreads();
    // stage cw = c*wm : 64x32 floats = 512 float4, 2/thread
    #pragma unroll
    for (int i = 0; i < 2; i++) {
      int idx4 = t + i * 256;
      int r = idx4 >> 3, dd = (idx4 & 7) * 4;
      float4 cv = *(const float4*)(c + (size_t)(b * NN + n0 + r) * DD + k0 + dd);
      float4 wv = *(const float4*)(wm + k0 + dd);
      cv.x *= wv.x; cv.y *= wv.y; cv.z *= wv.z; cv.w *= wv.w;
      *(float4*)(cw + r * 32 + dd) = cv;
    }
    // stage qs : 128x32 floats = 1024 float4, 4/thread
    #pragma unroll
    for (int i = 0; i < 4; i++) {
      int idx4 = t + i * 256;
      int m = idx4 >> 3, dd = (idx4 & 7) * 4;
      float4 qv = *(const float4*)(q + (size_t)(b * MM + m) * DD + k0 + dd);
      *(float4*)(qs + m * 36 + dd) = qv;
    }
    __syncthreads();
    #pragma unroll
    for (int dk = 0; dk < 32; dk += 4) {
      float4 av[8], bv[4];
      #pragma unroll
      for (int i = 0; i < 8; i++) av[i] = *(const float4*)(cw + (ty * 8 + i) * 32 + dk);
      #pragma unroll
      for (int j = 0; j < 4; j++) bv[j] = *(const float4*)(qs + (tx + j * 32) * 36 + dk);
      #pragma unroll
      for (int i = 0; i < 8; i++)
        #pragma unroll
        for (int j = 0; j < 4; j++)
          acc[i][j] += av[i].x * bv[j].x + av[i].y * bv[j].y +
                       av[i].z * bv[j].z + av[i].w * bv[j].w;
    }
  }

  // fused row softmax + writes (row r owned by the 32 lanes sharing ty)
  #pragma unroll
  for (int i = 0; i < 8; i++) {
    int gn = n0 + ty * 8 + i;
    float s0m = sub0[b * NN + gn] + (cmask[b * NN + gn] ? 0.0f : MASKV);
    float x[4], e[4];
    float vmax = -FLT_MAX;
    #pragma unroll
    for (int j = 0; j < 4; j++) { x[j] = acc[i][j] + qt[j]; vmax = fmaxf(vmax, x[j]); }
    #pragma unroll
    for (int off = 16; off > 0; off >>= 1) vmax = fmaxf(vmax, __shfl_xor(vmax, off, 64));
    float vsum = 0.0f;
    #pragma unroll
    for (int j = 0; j < 4; j++) { e[j] = __expf(x[j] - vmax); vsum += e[j]; }
    #pragma unroll
    for (int off = 16; off > 0; off >>= 1) vsum += __shfl_xor(vsum, off, 64);
    float inv = 1.0f / vsum;
    size_t base = (size_t)(b * NN + gn) * MM + tx;
    #pragma unroll
    for (int j = 0; j < 4; j++) {
      S_[base + j * 32] = e[j] * inv;
      T[base + j * 32] = acc[i][j] + s0m;
    }
  }
}

// ---------------------------------------------------------------------------
// K3a: partial column (over n) max/sum of T, chunks of 128 n. block = 128 thr.
// ---------------------------------------------------------------------------
__global__ __launch_bounds__(128) void k_colstat(
    const float* __restrict__ T, float* __restrict__ pmax, float* __restrict__ psum) {
  const int b = blockIdx.y, ch = blockIdx.x, m = threadIdx.x;
  float rm = -FLT_MAX, rs = 0.0f;
  size_t base = ((size_t)b * NN + ch * 128) * MM + m;
  for (int k = 0; k < 128; k++) {
    float v = T[base + (size_t)k * MM];
    float nm = fmaxf(rm, v);
    rs = rs * __expf(rm - nm) + __expf(v - nm);
    rm = nm;
  }
  pmax[(b * 8 + ch) * MM + m] = rm;
  psum[(b * 8 + ch) * MM + m] = rs;
}

// K3b: combine the 8 chunk partials -> colmax, colinv = 1/colsum
__global__ __launch_bounds__(256) void k_colcomb(
    const float* __restrict__ pmax, const float* __restrict__ psum,
    float* __restrict__ colmax, float* __restrict__ colinv) {
  int i = blockIdx.x * 256 + threadIdx.x;  // 0 .. B*M-1
  int b = i >> 7, m = i & 127;
  float Mx = -FLT_MAX;
  #pragma unroll
  for (int ch = 0; ch < 8; ch++) Mx = fmaxf(Mx, pmax[(b * 8 + ch) * MM + m]);
  float S = 0.0f;
  #pragma unroll
  for (int ch = 0; ch < 8; ch++)
    S += psum[(b * 8 + ch) * MM + m] * __expf(pmax[(b * 8 + ch) * MM + m] - Mx);
  colmax[i] = Mx;
  colinv[i] = 1.0f / S;
}

// zero A (ws is poisoned 0xAA each call)
__global__ __launch_bounds__(256) void k_zero(float* __restrict__ A) {
  size_t i = (size_t)blockIdx.x * 256 + threadIdx.x;
  ((float4*)A)[i] = make_float4(0.f, 0.f, 0.f, 0.f);
}

// ---------------------------------------------------------------------------
// K4: A[b,m,d] = colinv[m] * sum_n exp(T[b,n,m]-colmax[m]) * c[b,n,d]
// grid (8 dchunks of 32, 4 nchunks of 256, B). thread: m = t&127, 16 d's.
// T loads coalesced; c loads wave-broadcast. LDS transpose -> coalesced atomics.
// ---------------------------------------------------------------------------
__global__ __launch_bounds__(256) void k_colA(
    const float* __restrict__ T, const float* __restrict__ c,
    const float* __restrict__ colmax, const float* __restrict__ colinv,
    float* __restrict__ A) {
  __shared__ float lt[128 * 33];
  const int b = blockIdx.z;
  const int dbase = blockIdx.x * 32;
  const int n0 = blockIdx.y * 256;
  const int t = threadIdx.x;
  const int m = t & 127;
  const int dset = (t >> 7) * 16;
  const float cm = colmax[b * MM + m];
  float acc[16];
  #pragma unroll
  for (int k = 0; k < 16; k++) acc[k] = 0.0f;

  for (int nn = 0; nn < 256; nn++) {
    int n = n0 + nn;
    float tv = T[(size_t)(b * NN + n) * MM + m];
    float e = __expf(tv - cm);
    const float* cp = c + (size_t)(b * NN + n) * DD + dbase + dset;
    float4 c0 = *(const float4*)(cp);
    float4 c1 = *(const float4*)(cp + 4);
    float4 c2 = *(const float4*)(cp + 8);
    float4 c3 = *(const float4*)(cp + 12);
    acc[0]  += e * c0.x; acc[1]  += e * c0.y; acc[2]  += e * c0.z; acc[3]  += e * c0.w;
    acc[4]  += e * c1.x; acc[5]  += e * c1.y; acc[6]  += e * c1.z; acc[7]  += e * c1.w;
    acc[8]  += e * c2.x; acc[9]  += e * c2.y; acc[10] += e * c2.z; acc[11] += e * c2.w;
    acc[12] += e * c3.x; acc[13] += e * c3.y; acc[14] += e * c3.z; acc[15] += e * c3.w;
  }
  #pragma unroll
  for (int k = 0; k < 16; k++) lt[m * 33 + dset + k] = acc[k];
  __syncthreads();
  #pragma unroll
  for (int it = 0; it < 16; it++) {
    int idx = t + it * 256;            // 0..4095
    int mm = idx >> 5, dd = idx & 31;
    float val = lt[mm * 33 + dd] * colinv[b * MM + mm];
    atomicAdd(&A[(size_t)(b * MM + mm) * DD + dbase + dd], val);
  }
}

// ---------------------------------------------------------------------------
// K5: c2q = S_ @ q ; q2c = S_ @ A ; out = [c, c2q, c*c2q, c*q2c]
// block: 32 rows x 256 d ; per-thread 8 rows x 4 d (float4), S broadcast LDS.
// ---------------------------------------------------------------------------
__global__ __launch_bounds__(256) void k_out(
    const float* __restrict__ c, const float* __restrict__ q,
    const float* __restrict__ S_, const float* __restrict__ A,
    float* __restrict__ out) {
  __shared__ float s[32 * 128];
  const int b = blockIdx.y;
  const int n0 = blockIdx.x * 32;
  const int t = threadIdx.x;
  const int dx = t & 63, ry = t >> 6;  // ry = wave id

  size_t sbase = (size_t)(b * NN + n0) * MM;
  #pragma unroll
  for (int it = 0; it < 16; it++) {
    int idx = t + it * 256;
    s[idx] = S_[sbase + idx];
  }
  __syncthreads();

  float c2q[8][4], q2c[8][4];
  #pragma unroll
  for (int i = 0; i < 8; i++)
    #pragma unroll
    for (int k = 0; k < 4; k++) { c2q[i][k] = 0.f; q2c[i][k] = 0.f; }

  for (int m = 0; m < MM; m++) {
    float4 qv = *(const float4*)(q + (size_t)(b * MM + m) * DD + dx * 4);
    float4 av = *(const float4*)(A + (size_t)(b * MM + m) * DD + dx * 4);
    #pragma unroll
    for (int i = 0; i < 8; i++) {
      float sv = s[(ry * 8 + i) * 128 + m];
      c2q[i][0] += sv * qv.x; c2q[i][1] += sv * qv.y;
      c2q[i][2] += sv * qv.z; c2q[i][3] += sv * qv.w;
      q2c[i][0] += sv * av.x; q2c[i][1] += sv * av.y;
      q2c[i][2] += sv * av.z; q2c[i][3] += sv * av.w;
    }
  }

  #pragma unroll
  for (int i = 0; i < 8; i++) {
    int gn = n0 + ry * 8 + i;
    float4 cv = *(const float4*)(c + (size_t)(b * NN + gn) * DD + dx * 4);
    size_t ob = (size_t)(b * NN + gn) * (4 * DD) + dx * 4;
    float4 o1 = make_float4(c2q[i][0], c2q[i][1], c2q[i][2], c2q[i][3]);
    float4 o2 = make_float4(cv.x * o1.x, cv.y * o1.y, cv.z * o1.z, cv.w * o1.w);
    float4 o3 = make_float4(cv.x * q2c[i][0], cv.y * q2c[i][1],
                            cv.z * q2c[i][2], cv.w * q2c[i][3]);
    *(float4*)(out + ob)            = cv;
    *(float4*)(out + ob + DD)       = o1;
    *(float4*)(out + ob + 2 * DD)   = o2;
    *(float4*)(out + ob + 3 * DD)   = o3;
  }
}

// ---------------------------------------------------------------------------
extern "C" void kernel_launch(void* const* d_in, const int* in_sizes, int n_in,
                              void* d_out, int out_size, void* d_ws, size_t ws_size,
                              hipStream_t stream) {
  const float* c     = (const float*)d_in[0];
  const float* q     = (const float*)d_in[1];
  const int*   cmask = (const int*)d_in[2];
  const int*   qmask = (const int*)d_in[3];
  const float* w0    = (const float*)d_in[4];
  const float* w1    = (const float*)d_in[5];
  const float* wm    = (const float*)d_in[6];
  const float* bias  = (const float*)d_in[7];
  float* out = (float*)d_out;
  float* ws  = (float*)d_ws;

  float* S_     = ws;                  // B*N*M = 8388608
  float* T      = ws + 8388608;        // B*N*M
  float* A      = ws + 16777216;       // B*M*D = 2097152
  float* sub0   = ws + 18874368;       // B*N   = 65536
  float* qtermM = ws + 18939904;       // B*M   = 8192
  float* colmax = ws + 18948096;       // B*M
  float* colinv = ws + 18956288;       // B*M
  float* pmax   = ws + 18964480;       // B*8*M = 65536
  float* psum   = ws + 19030016;       // B*8*M

  k_dots<<<18432, 256, 0, stream>>>(c, q, qmask, w0, w1, bias, sub0, qtermM);
  k_score<<<dim3(16, BB), 256, 0, stream>>>(c, q, cmask, wm, sub0, qtermM, S_, T);
  k_zero<<<2048, 256, 0, stream>>>(A);
  k_colstat<<<dim3(8, BB), 128, 0, stream>>>(T, pmax, psum);
  k_colcomb<<<32, 256, 0, stream>>>(pmax, psum, colmax, colinv);
  k_colA<<<dim3(8, 4, BB), 256, 0, stream>>>(T, c, colmax, colinv, A);
  k_out<<<dim3(32, BB), 256, 0, stream>>>(c, q, S_, A, out);
}

// Round 2
// 607.242 us; speedup vs baseline: 1.3840x; 1.3840x over previous
//
#include <hip/hip_runtime.h>
#include <cfloat>

#define BB 64
#define NN 1024
#define MM 128
#define DD 256
#define MASKV (-1e30f)

// ---------------------------------------------------------------------------
// K1: sub0[b,n] = c[b,n,:].w0 ; qtermM[b,m] = q[b,m,:].w1 + bias[m] + MASK*(1-qm)
// one wave per row, float4 per lane, shuffle reduce
// ---------------------------------------------------------------------------
__global__ __launch_bounds__(256) void k_dots(
    const float* __restrict__ c, const float* __restrict__ q,
    const int* __restrict__ qmask,
    const float* __restrict__ w0, const float* __restrict__ w1,
    const float* __restrict__ bias,
    float* __restrict__ sub0, float* __restrict__ qtermM) {
  int wave = (blockIdx.x * blockDim.x + threadIdx.x) >> 6;
  int lane = threadIdx.x & 63;
  const int total = BB * NN + BB * MM;
  if (wave >= total) return;
  const float* row;
  const float* w;
  if (wave < BB * NN) { row = c + (size_t)wave * DD; w = w0; }
  else                { row = q + (size_t)(wave - BB * NN) * DD; w = w1; }
  float4 v  = *(const float4*)(row + lane * 4);
  float4 wv = *(const float4*)(w   + lane * 4);
  float s = v.x * wv.x + v.y * wv.y + v.z * wv.z + v.w * wv.w;
  #pragma unroll
  for (int off = 32; off > 0; off >>= 1) s += __shfl_xor(s, off, 64);
  if (lane == 0) {
    if (wave < BB * NN) {
      sub0[wave] = s;
    } else {
      int r = wave - BB * NN;
      int m = r & (MM - 1);
      qtermM[r] = s + bias[m] + (qmask[r] ? 0.0f : MASKV);
    }
  }
}

// zero colsum (ws is poisoned 0xAA each call)
__global__ __launch_bounds__(256) void k_zero(float* __restrict__ p) {
  p[blockIdx.x * 256 + threadIdx.x] = 0.0f;
}

// ---------------------------------------------------------------------------
// K2: sub2 tile GEMM (64 rows x 128 m, K=256) + fused row softmax (over m).
// Writes S_ (row-softmaxed) and E = exp(sub2 + sub0 + MASK*(1-cmask)); also
// accumulates colsum[b,m] += sum_n E via LDS reduce + atomicAdd.
// Per-thread tile: 8 rows x 4 m.  tx = t&31 -> m = tx + j*32 ; ty = t>>5 ->
// rows ty*8+i.  Row stats reduce across a 32-lane half-wave via shfl_xor.
// ---------------------------------------------------------------------------
__global__ __launch_bounds__(256) void k_score(
    const float* __restrict__ c, const float* __restrict__ q,
    const int* __restrict__ cmask, const float* __restrict__ wm,
    const float* __restrict__ sub0, const float* __restrict__ qtermM,
    float* __restrict__ S_, float* __restrict__ E,
    float* __restrict__ colsum) {
  __shared__ float cw[64 * 32];    // [r][dd], stride 32 (reads are broadcast)
  __shared__ float qs[128 * 36];   // [m][dd], stride 36 (16B aligned, low-conflict)
  __shared__ float lcs[8 * 128];   // [ty][m] colsum partials
  const int b = blockIdx.y;
  const int n0 = blockIdx.x * 64;
  const int t = threadIdx.x;
  const int tx = t & 31, ty = t >> 5;

  float acc[8][4];
  #pragma unroll
  for (int i = 0; i < 8; i++)
    #pragma unroll
    for (int j = 0; j < 4; j++) acc[i][j] = 0.0f;

  float qt[4];
  #pragma unroll
  for (int j = 0; j < 4; j++) qt[j] = qtermM[b * MM + tx + j * 32];

  for (int k0 = 0; k0 < DD; k0 += 32) {
    __syncthreads();
    // stage cw = c*wm : 64x32 floats = 512 float4, 2/thread
    #pragma unroll
    for (int i = 0; i < 2; i++) {
      int idx4 = t + i * 256;
      int r = idx4 >> 3, dd = (idx4 & 7) * 4;
      float4 cv = *(const float4*)(c + (size_t)(b * NN + n0 + r) * DD + k0 + dd);
      float4 wv = *(const float4*)(wm + k0 + dd);
      cv.x *= wv.x; cv.y *= wv.y; cv.z *= wv.z; cv.w *= wv.w;
      *(float4*)(cw + r * 32 + dd) = cv;
    }
    // stage qs : 128x32 floats = 1024 float4, 4/thread
    #pragma unroll
    for (int i = 0; i < 4; i++) {
      int idx4 = t + i * 256;
      int m = idx4 >> 3, dd = (idx4 & 7) * 4;
      float4 qv = *(const float4*)(q + (size_t)(b * MM + m) * DD + k0 + dd);
      *(float4*)(qs + m * 36 + dd) = qv;
    }
    __syncthreads();
    #pragma unroll
    for (int dk = 0; dk < 32; dk += 4) {
      float4 av[8], bv[4];
      #pragma unroll
      for (int i = 0; i < 8; i++) av[i] = *(const float4*)(cw + (ty * 8 + i) * 32 + dk);
      #pragma unroll
      for (int j = 0; j < 4; j++) bv[j] = *(const float4*)(qs + (tx + j * 32) * 36 + dk);
      #pragma unroll
      for (int i = 0; i < 8; i++)
        #pragma unroll
        for (int j = 0; j < 4; j++)
          acc[i][j] += av[i].x * bv[j].x + av[i].y * bv[j].y +
                       av[i].z * bv[j].z + av[i].w * bv[j].w;
    }
  }

  // fused row softmax + E + colsum partials
  float ps[4] = {0.f, 0.f, 0.f, 0.f};
  #pragma unroll
  for (int i = 0; i < 8; i++) {
    int gn = n0 + ty * 8 + i;
    float s0m = sub0[b * NN + gn] + (cmask[b * NN + gn] ? 0.0f : MASKV);
    float x[4], e[4];
    float vmax = -FLT_MAX;
    #pragma unroll
    for (int j = 0; j < 4; j++) { x[j] = acc[i][j] + qt[j]; vmax = fmaxf(vmax, x[j]); }
    #pragma unroll
    for (int off = 16; off > 0; off >>= 1) vmax = fmaxf(vmax, __shfl_xor(vmax, off, 64));
    float vsum = 0.0f;
    #pragma unroll
    for (int j = 0; j < 4; j++) { e[j] = __expf(x[j] - vmax); vsum += e[j]; }
    #pragma unroll
    for (int off = 16; off > 0; off >>= 1) vsum += __shfl_xor(vsum, off, 64);
    float inv = 1.0f / vsum;
    size_t base = (size_t)(b * NN + gn) * MM + tx;
    #pragma unroll
    for (int j = 0; j < 4; j++) {
      S_[base + j * 32] = e[j] * inv;
      float Ev = __expf(acc[i][j] + s0m);   // exp(-1e30+x) underflows to 0 exactly
      E[base + j * 32] = Ev;
      ps[j] += Ev;
    }
  }

  // reduce colsum partials over the 8 ty-groups, one atomic per (block, m)
  #pragma unroll
  for (int j = 0; j < 4; j++) lcs[ty * 128 + tx + j * 32] = ps[j];
  __syncthreads();
  if (t < 128) {
    float s = 0.0f;
    #pragma unroll
    for (int g = 0; g < 8; g++) s += lcs[g * 128 + t];
    atomicAdd(&colsum[b * MM + t], s);
  }
}

// ---------------------------------------------------------------------------
// K4: A[b,m,d] = (sum_n E[b,n,m] * c[b,n,d]) / colsum[b,m]
// LDS-tiled register GEMM: 64m x 64d tile, NK=32, 4x4 per-thread tile,
// software-pipelined global->reg prefetch. grid (2 mtiles, 4 dtiles, B).
// ---------------------------------------------------------------------------
__global__ __launch_bounds__(256) void k_colA(
    const float* __restrict__ E, const float* __restrict__ c,
    const float* __restrict__ colsum, float* __restrict__ A) {
  __shared__ float se[32 * 64];   // [nk][m]
  __shared__ float sc[32 * 64];   // [nk][d]
  const int b = blockIdx.z;
  const int m0 = blockIdx.x * 64;
  const int d0 = blockIdx.y * 64;
  const int t = threadIdx.x;
  const int tx = t & 15;          // d group
  const int ty = t >> 4;          // m group
  const int lr = t >> 4;          // staging row (0..15), +16 for second half
  const int lc = (t & 15) * 4;    // staging col

  const float* Eb = E + (size_t)b * NN * MM + m0 + lc;
  const float* cb = c + (size_t)b * NN * DD + d0 + lc;

  float4 ev0 = *(const float4*)(Eb + (size_t)lr * MM);
  float4 ev1 = *(const float4*)(Eb + (size_t)(16 + lr) * MM);
  float4 cv0 = *(const float4*)(cb + (size_t)lr * DD);
  float4 cv1 = *(const float4*)(cb + (size_t)(16 + lr) * DD);

  float acc[4][4];
  #pragma unroll
  for (int mi = 0; mi < 4; mi++)
    #pragma unroll
    for (int di = 0; di < 4; di++) acc[mi][di] = 0.0f;

  for (int n0 = 0; n0 < NN; n0 += 32) {
    *(float4*)(&se[lr * 64 + lc])        = ev0;
    *(float4*)(&se[(16 + lr) * 64 + lc]) = ev1;
    *(float4*)(&sc[lr * 64 + lc])        = cv0;
    *(float4*)(&sc[(16 + lr) * 64 + lc]) = cv1;
    __syncthreads();
    if (n0 + 32 < NN) {
      int nn = n0 + 32;
      ev0 = *(const float4*)(Eb + (size_t)(nn + lr) * MM);
      ev1 = *(const float4*)(Eb + (size_t)(nn + 16 + lr) * MM);
      cv0 = *(const float4*)(cb + (size_t)(nn + lr) * DD);
      cv1 = *(const float4*)(cb + (size_t)(nn + 16 + lr) * DD);
    }
    #pragma unroll
    for (int kk = 0; kk < 32; kk++) {
      float4 e4 = *(const float4*)(&se[kk * 64 + ty * 4]);
      float4 c4 = *(const float4*)(&sc[kk * 64 + tx * 4]);
      float em[4] = {e4.x, e4.y, e4.z, e4.w};
      float cd[4] = {c4.x, c4.y, c4.z, c4.w};
      #pragma unroll
      for (int mi = 0; mi < 4; mi++)
        #pragma unroll
        for (int di = 0; di < 4; di++) acc[mi][di] += em[mi] * cd[di];
    }
    __syncthreads();
  }

  #pragma unroll
  for (int mi = 0; mi < 4; mi++) {
    int m = m0 + ty * 4 + mi;
    float inv = 1.0f / colsum[b * MM + m];
    float4 o = make_float4(acc[mi][0] * inv, acc[mi][1] * inv,
                           acc[mi][2] * inv, acc[mi][3] * inv);
    *(float4*)(A + (size_t)(b * MM + m) * DD + d0 + tx * 4) = o;
  }
}

// ---------------------------------------------------------------------------
// K5: c2q = S_ @ q ; q2c = S_ @ A ; out = [c, c2q, c*c2q, c*q2c]
// block: 32 rows x 256 d ; per-thread 8 rows x 4 d (float4), S broadcast LDS.
// ---------------------------------------------------------------------------
__global__ __launch_bounds__(256) void k_out(
    const float* __restrict__ c, const float* __restrict__ q,
    const float* __restrict__ S_, const float* __restrict__ A,
    float* __restrict__ out) {
  __shared__ float s[32 * 128];
  const int b = blockIdx.y;
  const int n0 = blockIdx.x * 32;
  const int t = threadIdx.x;
  const int dx = t & 63, ry = t >> 6;  // ry = wave id

  size_t sbase = (size_t)(b * NN + n0) * MM;
  #pragma unroll
  for (int it = 0; it < 16; it++) {
    int idx = t + it * 256;
    s[idx] = S_[sbase + idx];
  }
  __syncthreads();

  float c2q[8][4], q2c[8][4];
  #pragma unroll
  for (int i = 0; i < 8; i++)
    #pragma unroll
    for (int k = 0; k < 4; k++) { c2q[i][k] = 0.f; q2c[i][k] = 0.f; }

  for (int m = 0; m < MM; m++) {
    float4 qv = *(const float4*)(q + (size_t)(b * MM + m) * DD + dx * 4);
    float4 av = *(const float4*)(A + (size_t)(b * MM + m) * DD + dx * 4);
    #pragma unroll
    for (int i = 0; i < 8; i++) {
      float sv = s[(ry * 8 + i) * 128 + m];
      c2q[i][0] += sv * qv.x; c2q[i][1] += sv * qv.y;
      c2q[i][2] += sv * qv.z; c2q[i][3] += sv * qv.w;
      q2c[i][0] += sv * av.x; q2c[i][1] += sv * av.y;
      q2c[i][2] += sv * av.z; q2c[i][3] += sv * av.w;
    }
  }

  #pragma unroll
  for (int i = 0; i < 8; i++) {
    int gn = n0 + ry * 8 + i;
    float4 cv = *(const float4*)(c + (size_t)(b * NN + gn) * DD + dx * 4);
    size_t ob = (size_t)(b * NN + gn) * (4 * DD) + dx * 4;
    float4 o1 = make_float4(c2q[i][0], c2q[i][1], c2q[i][2], c2q[i][3]);
    float4 o2 = make_float4(cv.x * o1.x, cv.y * o1.y, cv.z * o1.z, cv.w * o1.w);
    float4 o3 = make_float4(cv.x * q2c[i][0], cv.y * q2c[i][1],
                            cv.z * q2c[i][2], cv.w * q2c[i][3]);
    *(float4*)(out + ob)            = cv;
    *(float4*)(out + ob + DD)       = o1;
    *(float4*)(out + ob + 2 * DD)   = o2;
    *(float4*)(out + ob + 3 * DD)   = o3;
  }
}

// ---------------------------------------------------------------------------
extern "C" void kernel_launch(void* const* d_in, const int* in_sizes, int n_in,
                              void* d_out, int out_size, void* d_ws, size_t ws_size,
                              hipStream_t stream) {
  const float* c     = (const float*)d_in[0];
  const float* q     = (const float*)d_in[1];
  const int*   cmask = (const int*)d_in[2];
  const int*   qmask = (const int*)d_in[3];
  const float* w0    = (const float*)d_in[4];
  const float* w1    = (const float*)d_in[5];
  const float* wm    = (const float*)d_in[6];
  const float* bias  = (const float*)d_in[7];
  float* out = (float*)d_out;
  float* ws  = (float*)d_ws;

  float* S_     = ws;                  // B*N*M = 8388608
  float* E      = ws + 8388608;        // B*N*M
  float* A      = ws + 16777216;       // B*M*D = 2097152
  float* sub0   = ws + 18874368;       // B*N   = 65536
  float* qtermM = ws + 18939904;       // B*M   = 8192
  float* colsum = ws + 18948096;       // B*M   = 8192

  k_dots<<<18432, 256, 0, stream>>>(c, q, qmask, w0, w1, bias, sub0, qtermM);
  k_zero<<<32, 256, 0, stream>>>(colsum);
  k_score<<<dim3(16, BB), 256, 0, stream>>>(c, q, cmask, wm, sub0, qtermM, S_, E, colsum);
  k_colA<<<dim3(2, 4, BB), 256, 0, stream>>>(E, c, colsum, A);
  k_out<<<dim3(32, BB), 256, 0, stream>>>(c, q, S_, A, out);
}